// Round 7
// baseline (210.209 us; speedup 1.0000x reference)
//
#include <hip/hip_runtime.h>

// SynthMorphLoss: soft-dice over int32 label maps + diffusion regularizer.
// B=1, D=160, H=192, W=224, 26 classes (class 0 ignored in dice mean).
// R13: attack the FIXED cost. Empirical: total == fused + 117.3 +/- 0.2 us
// across R7/R9/R10/R12 — the non-fused overhead is 2x the kernel. Fold
// finalize into fused via done-ticket (3 dispatches -> 2). R8's container
// death is now explained as an OOB ticket at ws offset 3616 (proven
// footprint ends at 3608); R13's ticket lives at offset 3432 — the free gap
// after the 858 joint bins, INSIDE the footprint every passing round used.
// Kernel bodies are R12-verbatim (dual-chain diff 58.3us, hist, z-carry).
// No spins: one ACQ_REL ticket RMW per block; last block's wave 0
// finalizes with device-scope loads (ticket acquire orders all flushes).

namespace {
constexpr int NC    = 26;
constexpr int Dd    = 160, Hh = 192, Ww = 224;
constexpr int W4    = Ww / 4;                 // 56 float4 per row
constexpr int PL4   = Hh * W4;                // 10752 float4 per (c,d) plane
constexpr int N4L   = Dd * Hh * Ww / 4;       // 1,720,320 int4 per label map
constexpr int JSTRIDE = 33;                   // joint-hist row stride
constexpr int NBINS   = NC * JSTRIDE;         // 858
constexpr int TPB     = 512;                  // 8 waves per block
constexpr int WPB     = TPB / 64;             // 8
// hist: 420 blocks x 512 threads x 8 int4 per map (420*512*8 == N4L exact)
constexpr int HIST_BLOCKS = 420;
constexpr int HT          = HIST_BLOCKS * TPB;     // 215040
// diff: tile = (c, 6-row h-slab, 5-plane d-chunk); 3072 tiles total.
// Each wave owns TWO tiles: w and w + 1536.
constexpr int SLAB    = 6;                    // rows per tile
constexpr int DCH     = 5;                    // d-steps per tile
constexpr int NTILES  = 3 * (Dd / DCH) * (Hh / SLAB);  // 3072
constexpr int DIFF_WAVES  = NTILES / 2;                // 1536
constexpr int DIFF_BLOCKS = DIFF_WAVES / WPB;          // 192
constexpr int FUSED_BLOCKS = DIFF_BLOCKS + HIST_BLOCKS;  // 612
}

__global__ void init_ws_kernel(unsigned int* __restrict__ joint,
                               double* __restrict__ sums,
                               unsigned int* __restrict__ done) {
    int i = blockIdx.x * blockDim.x + threadIdx.x;
    if (i < NBINS) joint[i] = 0u;
    if (i < 3)     sums[i]  = 0.0;
    if (i == 0)    done[0]  = 0u;
}

// ---- hist path: same per-thread work as R6-R12 (8 int4 per map) ----
__device__ __forceinline__ void hist_path(
        int hb,
        const int4* __restrict__ f4,
        const int4* __restrict__ m4,
        unsigned int* __restrict__ gj) {
    __shared__ unsigned int h[NBINS];
    for (int i = threadIdx.x; i < NBINS; i += TPB) h[i] = 0u;
    __syncthreads();

    const int g = hb * TPB + threadIdx.x;
    int4 a0 = f4[g];
    int4 a1 = f4[g + HT];
    int4 a2 = f4[g + 2 * HT];
    int4 a3 = f4[g + 3 * HT];
    int4 a4 = f4[g + 4 * HT];
    int4 a5 = f4[g + 5 * HT];
    int4 a6 = f4[g + 6 * HT];
    int4 a7 = f4[g + 7 * HT];
    int4 b0 = m4[g];
    int4 b1 = m4[g + HT];
    int4 b2 = m4[g + 2 * HT];
    int4 b3 = m4[g + 3 * HT];
    int4 b4 = m4[g + 4 * HT];
    int4 b5 = m4[g + 5 * HT];
    int4 b6 = m4[g + 6 * HT];
    int4 b7 = m4[g + 7 * HT];

#define JACC(A, B)                                   \
    atomicAdd(&h[(A).x * JSTRIDE + (B).x], 1u);      \
    atomicAdd(&h[(A).y * JSTRIDE + (B).y], 1u);      \
    atomicAdd(&h[(A).z * JSTRIDE + (B).z], 1u);      \
    atomicAdd(&h[(A).w * JSTRIDE + (B).w], 1u);
    JACC(a0, b0) JACC(a1, b1) JACC(a2, b2) JACC(a3, b3)
    JACC(a4, b4) JACC(a5, b5) JACC(a6, b6) JACC(a7, b7)
#undef JACC

    __syncthreads();
    for (int i = threadIdx.x; i < NBINS; i += TPB) {
        unsigned int v = h[i];
        if (v) atomicAdd(&gj[i], v);
    }
}

// ---- diff path: TWO independent z-carry chains per wave (R12 verbatim) ----
__device__ __forceinline__ void diff_path(
        int db,
        const float4* __restrict__ v4,
        double* __restrict__ gs) {
    const int lane = threadIdx.x & 63;
    const int wid  = threadIdx.x >> 6;
    const int w    = db * WPB + wid;          // 0..1535
    const bool al  = (lane < W4);
    const int  l   = al ? lane : (W4 - 1);    // clamp inactive lanes

    // tile A
    const int tA = w;
    const int cA = tA >> 10, remA = tA & 1023;
    const int d0A = (remA >> 5) * DCH;
    const int h0A = (remA & 31) * SLAB;
    const bool hvA = (h0A + SLAB < Hh);
    const int hOffA = (hvA ? SLAB : SLAB - 1) * W4;
    size_t curA = ((size_t)(cA * Dd + d0A) * Hh + h0A) * W4 + l;
    // tile B
    const int tB = w + DIFF_WAVES;
    const int cB = tB >> 10, remB = tB & 1023;
    const int d0B = (remB >> 5) * DCH;
    const int h0B = (remB & 31) * SLAB;
    const bool hvB = (h0B + SLAB < Hh);
    const int hOffB = (hvB ? SLAB : SLAB - 1) * W4;
    size_t curB = ((size_t)(cB * Dd + d0B) * Hh + h0B) * W4 + l;

    float4 pA0 = v4[curA];
    float4 pA1 = v4[curA + W4];
    float4 pA2 = v4[curA + 2 * W4];
    float4 pA3 = v4[curA + 3 * W4];
    float4 pA4 = v4[curA + 4 * W4];
    float4 pA5 = v4[curA + 5 * W4];
    float4 pB0 = v4[curB];
    float4 pB1 = v4[curB + W4];
    float4 pB2 = v4[curB + 2 * W4];
    float4 pB3 = v4[curB + 3 * W4];
    float4 pB4 = v4[curB + 4 * W4];
    float4 pB5 = v4[curB + 5 * W4];

    float sx = 0.f, sy = 0.f, sz = 0.f;

#define DX(P)                                                                  \
    {                                                                          \
        float d1 = (P).y - (P).x, d2 = (P).z - (P).y, d3 = (P).w - (P).z;      \
        sx += d1 * d1 + d2 * d2 + d3 * d3;                                     \
        float nx = __shfl_down((P).x, 1);                                      \
        float d4 = nx - (P).w;                                                 \
        sx += (lane < W4 - 1) ? d4 * d4 : 0.f;                                 \
    }
#define DY(A, B)                                                               \
    {                                                                          \
        float e0 = (B).x - (A).x, e1 = (B).y - (A).y;                          \
        float e2 = (B).z - (A).z, e3 = (B).w - (A).w;                          \
        sy += e0 * e0 + e1 * e1 + e2 * e2 + e3 * e3;                           \
    }
#define DZ(A, B)                                                               \
    {                                                                          \
        float e0 = (B).x - (A).x, e1 = (B).y - (A).y;                          \
        float e2 = (B).z - (A).z, e3 = (B).w - (A).w;                          \
        sz += e0 * e0 + e1 * e1 + e2 * e2 + e3 * e3;                           \
    }

    for (int k = 0; k < DCH; ++k) {
        const bool dzvA = (d0A + k < Dd - 1);     // wave-uniform
        const bool dzvB = (d0B + k < Dd - 1);
        // issue BOTH halo loads + BOTH next-plane clusters up front
        float4 hlA = v4[curA + hOffA];
        float4 hlB = v4[curB + hOffB];
        float4 nA0 = pA0, nA1 = pA1, nA2 = pA2, nA3 = pA3, nA4 = pA4, nA5 = pA5;
        if (dzvA) {
            const size_t nb = curA + PL4;
            nA0 = v4[nb];
            nA1 = v4[nb + W4];
            nA2 = v4[nb + 2 * W4];
            nA3 = v4[nb + 3 * W4];
            nA4 = v4[nb + 4 * W4];
            nA5 = v4[nb + 5 * W4];
        }
        float4 nB0 = pB0, nB1 = pB1, nB2 = pB2, nB3 = pB3, nB4 = pB4, nB5 = pB5;
        if (dzvB) {
            const size_t nb = curB + PL4;
            nB0 = v4[nb];
            nB1 = v4[nb + W4];
            nB2 = v4[nb + 2 * W4];
            nB3 = v4[nb + 3 * W4];
            nB4 = v4[nb + 4 * W4];
            nB5 = v4[nb + 5 * W4];
        }

        // chain A compute
        DX(pA0) DX(pA1) DX(pA2) DX(pA3) DX(pA4) DX(pA5)
        DY(pA0, pA1) DY(pA1, pA2) DY(pA2, pA3) DY(pA3, pA4) DY(pA4, pA5)
        if (hvA) DY(pA5, hlA)
        if (dzvA) {
            DZ(pA0, nA0) DZ(pA1, nA1) DZ(pA2, nA2)
            DZ(pA3, nA3) DZ(pA4, nA4) DZ(pA5, nA5)
        }
        // chain B compute
        DX(pB0) DX(pB1) DX(pB2) DX(pB3) DX(pB4) DX(pB5)
        DY(pB0, pB1) DY(pB1, pB2) DY(pB2, pB3) DY(pB3, pB4) DY(pB4, pB5)
        if (hvB) DY(pB5, hlB)
        if (dzvB) {
            DZ(pB0, nB0) DZ(pB1, nB1) DZ(pB2, nB2)
            DZ(pB3, nB3) DZ(pB4, nB4) DZ(pB5, nB5)
        }

        pA0 = nA0; pA1 = nA1; pA2 = nA2; pA3 = nA3; pA4 = nA4; pA5 = nA5;
        pB0 = nB0; pB1 = nB1; pB2 = nB2; pB3 = nB3; pB4 = nB4; pB5 = nB5;
        curA += PL4; curB += PL4;
    }
#undef DX
#undef DY
#undef DZ

    if (!al) { sx = 0.f; sy = 0.f; sz = 0.f; }    // clamped lanes: drop dupes

    #pragma unroll
    for (int off = 32; off > 0; off >>= 1) {
        sx += __shfl_down(sx, off);
        sy += __shfl_down(sy, off);
        sz += __shfl_down(sz, off);
    }
    __shared__ float px[WPB], py[WPB], pz[WPB];
    if (lane == 0) { px[wid] = sx; py[wid] = sy; pz[wid] = sz; }
    __syncthreads();
    if (threadIdx.x == 0) {
        float tx = 0.f, ty = 0.f, tz = 0.f;
        #pragma unroll
        for (int i = 0; i < WPB; ++i) { tx += px[i]; ty += py[i]; tz += pz[i]; }
        atomicAdd(&gs[0], (double)tx);
        atomicAdd(&gs[1], (double)ty);
        atomicAdd(&gs[2], (double)tz);
    }
}

// 612 blocks of 512 threads: diff blocks [0,192) first, hist behind.
// Last block to finish its flush runs the finalize (done-ticket).
__global__ __launch_bounds__(512, 2) void fused_kernel(
        const int4* __restrict__ f4,
        const int4* __restrict__ m4,
        unsigned int* __restrict__ gj,
        const float4* __restrict__ v4,
        double* __restrict__ gs,
        unsigned int* __restrict__ done,
        float* __restrict__ out) {
    if (blockIdx.x < DIFF_BLOCKS) diff_path(blockIdx.x, v4, gs);
    else                          hist_path(blockIdx.x - DIFF_BLOCKS, f4, m4, gj);

    // ---- done-ticket: one ACQ_REL RMW per block, no spinning ----
    __shared__ bool isLast;
    __syncthreads();                  // block's flush atomics are issued
    if (threadIdx.x == 0) {
        __threadfence();              // release: flushes visible device-wide
        unsigned int prev = __hip_atomic_fetch_add(
            done, 1u, __ATOMIC_ACQ_REL, __HIP_MEMORY_SCOPE_AGENT);
        isLast = (prev == (unsigned int)(FUSED_BLOCKS - 1));
    }
    __syncthreads();
    if (isLast && threadIdx.x < 64) {     // wave 0 of the last block
        const int ln = threadIdx.x;
        float term = 0.f;
        if (ln >= 1 && ln < NC) {
            float fv = 0.f, mv = 0.f;
            #pragma unroll
            for (int m = 0; m < NC; ++m)
                fv += (float)__hip_atomic_load(&gj[ln * JSTRIDE + m],
                        __ATOMIC_RELAXED, __HIP_MEMORY_SCOPE_AGENT);
            #pragma unroll
            for (int f = 0; f < NC; ++f)
                mv += (float)__hip_atomic_load(&gj[f * JSTRIDE + ln],
                        __ATOMIC_RELAXED, __HIP_MEMORY_SCOPE_AGENT);
            float iv = (float)__hip_atomic_load(&gj[ln * JSTRIDE + ln],
                        __ATOMIC_RELAXED, __HIP_MEMORY_SCOPE_AGENT);
            term = (2.f * iv + 1e-5f) / (fv + mv + 1e-5f);
        }
        #pragma unroll
        for (int off = 32; off > 0; off >>= 1) term += __shfl_down(term, off);
        if (ln == 0) {
            double g0 = __hip_atomic_load(&gs[0], __ATOMIC_RELAXED,
                                          __HIP_MEMORY_SCOPE_AGENT);
            double g1 = __hip_atomic_load(&gs[1], __ATOMIC_RELAXED,
                                          __HIP_MEMORY_SCOPE_AGENT);
            double g2 = __hip_atomic_load(&gs[2], __ATOMIC_RELAXED,
                                          __HIP_MEMORY_SCOPE_AGENT);
            float sim = 1.f - term * (1.f / 25.f);
            double mdx = g0 / ((double)3 * Dd * Hh * (Ww - 1));
            double mdy = g1 / ((double)3 * Dd * (Hh - 1) * Ww);
            double mdz = g2 / ((double)3 * (Dd - 1) * Hh * Ww);
            float smooth = (float)((mdx + mdy + mdz) / 3.0);
            out[0] = sim + smooth;
            out[1] = sim;
            out[2] = smooth;
        }
    }
}

extern "C" void kernel_launch(void* const* d_in, const int* in_sizes, int n_in,
                              void* d_out, int out_size, void* d_ws, size_t ws_size,
                              hipStream_t stream) {
    const int*   fl = (const int*)d_in[0];
    const int*   ml = (const int*)d_in[1];
    const float* vf = (const float*)d_in[2];
    float* out = (float*)d_out;

    // workspace layout (all inside the proven [0,3608) footprint):
    //   [0, 3432)    joint counts (858 uints)
    //   [3432, 3436) done ticket          <- was 3616 in R8 (OOB suspect)
    //   [3584, 3608) double sums[3]
    unsigned int* joint = (unsigned int*)d_ws;
    unsigned int* done  = (unsigned int*)((char*)d_ws + 3432);
    double*       sums  = (double*)((char*)d_ws + 3584);

    init_ws_kernel<<<1, 1024, 0, stream>>>(joint, sums, done);
    fused_kernel<<<FUSED_BLOCKS, TPB, 0, stream>>>(
        (const int4*)fl, (const int4*)ml, joint, (const float4*)vf, sums,
        done, out);
}

// Round 8
// 207.465 us; speedup vs baseline: 1.0132x; 1.0132x over previous
//
#include <hip/hip_runtime.h>

// SynthMorphLoss: soft-dice over int32 label maps + diffusion regularizer.
// B=1, D=160, H=192, W=224, 26 classes (class 0 ignored in dice mean).
// R14: R12 base (58.3us fused, best) + two separable fixes.
// (1) Diff tail CU-spread: R12's 192 diff blocks (dispatched first) occupy
//     only 192/256 CUs; after hist drains, 25% of CUs idle through the
//     diff tail. Same dual-chain waves in 256-thr blocks -> 384 diff
//     blocks ~ 1.5/CU. Hist in R7-proven 840x256 blocks behind.
// (2) init kernel -> hipMemsetAsync(d_ws, 0, 3608): removing the finalize
//     dispatch in R13 cut fixed cost 117.3 -> 105.5us (a dispatch ~ 11us);
//     memset node may be cheaper than a kernel dispatch.
// R13 post-mortem: done-ticket finalize cost +46us IN-kernel (block-retire
// throttled by per-block fence+agent-RMW tails) — cross-block sync is
// permanently off the table. Finalize stays a separate tiny dispatch.

namespace {
constexpr int NC    = 26;
constexpr int Dd    = 160, Hh = 192, Ww = 224;
constexpr int W4    = Ww / 4;                 // 56 float4 per row
constexpr int PL4   = Hh * W4;                // 10752 float4 per (c,d) plane
constexpr int N4L   = Dd * Hh * Ww / 4;       // 1,720,320 int4 per label map
constexpr int JSTRIDE = 33;                   // joint-hist row stride
constexpr int NBINS   = NC * JSTRIDE;         // 858
constexpr int TPB     = 256;                  // 4 waves per block
constexpr int WPB     = TPB / 64;             // 4
// hist: 840 blocks x 256 threads x 8 int4 per map (840*256*8 == N4L exact)
constexpr int HIST_BLOCKS = 840;
constexpr int HT          = HIST_BLOCKS * TPB;     // 215040
// diff: tile = (c, 6-row h-slab, 5-plane d-chunk); 3072 tiles total.
// Each wave owns TWO tiles: w and w + 1536 (dual-chain, R12-proven).
constexpr int SLAB    = 6;                    // rows per tile
constexpr int DCH     = 5;                    // d-steps per tile
constexpr int NTILES  = 3 * (Dd / DCH) * (Hh / SLAB);  // 3072
constexpr int DIFF_WAVES  = NTILES / 2;                // 1536
constexpr int DIFF_BLOCKS = DIFF_WAVES / WPB;          // 384
constexpr int FUSED_BLOCKS = DIFF_BLOCKS + HIST_BLOCKS;  // 1224
}

// ---- hist path: R7-proven body (8 int4 per map, 256-thr block) ----
__device__ __forceinline__ void hist_path(
        int hb,
        const int4* __restrict__ f4,
        const int4* __restrict__ m4,
        unsigned int* __restrict__ gj) {
    __shared__ unsigned int h[NBINS];
    for (int i = threadIdx.x; i < NBINS; i += TPB) h[i] = 0u;
    __syncthreads();

    const int g = hb * TPB + threadIdx.x;
    int4 a0 = f4[g];
    int4 a1 = f4[g + HT];
    int4 a2 = f4[g + 2 * HT];
    int4 a3 = f4[g + 3 * HT];
    int4 a4 = f4[g + 4 * HT];
    int4 a5 = f4[g + 5 * HT];
    int4 a6 = f4[g + 6 * HT];
    int4 a7 = f4[g + 7 * HT];
    int4 b0 = m4[g];
    int4 b1 = m4[g + HT];
    int4 b2 = m4[g + 2 * HT];
    int4 b3 = m4[g + 3 * HT];
    int4 b4 = m4[g + 4 * HT];
    int4 b5 = m4[g + 5 * HT];
    int4 b6 = m4[g + 6 * HT];
    int4 b7 = m4[g + 7 * HT];

#define JACC(A, B)                                   \
    atomicAdd(&h[(A).x * JSTRIDE + (B).x], 1u);      \
    atomicAdd(&h[(A).y * JSTRIDE + (B).y], 1u);      \
    atomicAdd(&h[(A).z * JSTRIDE + (B).z], 1u);      \
    atomicAdd(&h[(A).w * JSTRIDE + (B).w], 1u);
    JACC(a0, b0) JACC(a1, b1) JACC(a2, b2) JACC(a3, b3)
    JACC(a4, b4) JACC(a5, b5) JACC(a6, b6) JACC(a7, b7)
#undef JACC

    __syncthreads();
    for (int i = threadIdx.x; i < NBINS; i += TPB) {
        unsigned int v = h[i];
        if (v) atomicAdd(&gj[i], v);
    }
}

// ---- diff path: TWO independent z-carry chains per wave (R12 verbatim) ----
// Tile t: c = t>>10, dchunk = (t&1023)>>5, slab = t&31.
__device__ __forceinline__ void diff_path(
        int db,
        const float4* __restrict__ v4,
        double* __restrict__ gs) {
    const int lane = threadIdx.x & 63;
    const int wid  = threadIdx.x >> 6;
    const int w    = db * WPB + wid;          // 0..1535
    const bool al  = (lane < W4);
    const int  l   = al ? lane : (W4 - 1);    // clamp inactive lanes

    // tile A
    const int tA = w;
    const int cA = tA >> 10, remA = tA & 1023;
    const int d0A = (remA >> 5) * DCH;
    const int h0A = (remA & 31) * SLAB;
    const bool hvA = (h0A + SLAB < Hh);
    const int hOffA = (hvA ? SLAB : SLAB - 1) * W4;
    size_t curA = ((size_t)(cA * Dd + d0A) * Hh + h0A) * W4 + l;
    // tile B
    const int tB = w + DIFF_WAVES;
    const int cB = tB >> 10, remB = tB & 1023;
    const int d0B = (remB >> 5) * DCH;
    const int h0B = (remB & 31) * SLAB;
    const bool hvB = (h0B + SLAB < Hh);
    const int hOffB = (hvB ? SLAB : SLAB - 1) * W4;
    size_t curB = ((size_t)(cB * Dd + d0B) * Hh + h0B) * W4 + l;

    float4 pA0 = v4[curA];
    float4 pA1 = v4[curA + W4];
    float4 pA2 = v4[curA + 2 * W4];
    float4 pA3 = v4[curA + 3 * W4];
    float4 pA4 = v4[curA + 4 * W4];
    float4 pA5 = v4[curA + 5 * W4];
    float4 pB0 = v4[curB];
    float4 pB1 = v4[curB + W4];
    float4 pB2 = v4[curB + 2 * W4];
    float4 pB3 = v4[curB + 3 * W4];
    float4 pB4 = v4[curB + 4 * W4];
    float4 pB5 = v4[curB + 5 * W4];

    float sx = 0.f, sy = 0.f, sz = 0.f;

#define DX(P)                                                                  \
    {                                                                          \
        float d1 = (P).y - (P).x, d2 = (P).z - (P).y, d3 = (P).w - (P).z;      \
        sx += d1 * d1 + d2 * d2 + d3 * d3;                                     \
        float nx = __shfl_down((P).x, 1);                                      \
        float d4 = nx - (P).w;                                                 \
        sx += (lane < W4 - 1) ? d4 * d4 : 0.f;                                 \
    }
#define DY(A, B)                                                               \
    {                                                                          \
        float e0 = (B).x - (A).x, e1 = (B).y - (A).y;                          \
        float e2 = (B).z - (A).z, e3 = (B).w - (A).w;                          \
        sy += e0 * e0 + e1 * e1 + e2 * e2 + e3 * e3;                           \
    }
#define DZ(A, B)                                                               \
    {                                                                          \
        float e0 = (B).x - (A).x, e1 = (B).y - (A).y;                          \
        float e2 = (B).z - (A).z, e3 = (B).w - (A).w;                          \
        sz += e0 * e0 + e1 * e1 + e2 * e2 + e3 * e3;                           \
    }

    for (int k = 0; k < DCH; ++k) {
        const bool dzvA = (d0A + k < Dd - 1);     // wave-uniform
        const bool dzvB = (d0B + k < Dd - 1);
        // issue BOTH halo loads + BOTH next-plane clusters up front
        float4 hlA = v4[curA + hOffA];
        float4 hlB = v4[curB + hOffB];
        float4 nA0 = pA0, nA1 = pA1, nA2 = pA2, nA3 = pA3, nA4 = pA4, nA5 = pA5;
        if (dzvA) {
            const size_t nb = curA + PL4;
            nA0 = v4[nb];
            nA1 = v4[nb + W4];
            nA2 = v4[nb + 2 * W4];
            nA3 = v4[nb + 3 * W4];
            nA4 = v4[nb + 4 * W4];
            nA5 = v4[nb + 5 * W4];
        }
        float4 nB0 = pB0, nB1 = pB1, nB2 = pB2, nB3 = pB3, nB4 = pB4, nB5 = pB5;
        if (dzvB) {
            const size_t nb = curB + PL4;
            nB0 = v4[nb];
            nB1 = v4[nb + W4];
            nB2 = v4[nb + 2 * W4];
            nB3 = v4[nb + 3 * W4];
            nB4 = v4[nb + 4 * W4];
            nB5 = v4[nb + 5 * W4];
        }

        // chain A compute
        DX(pA0) DX(pA1) DX(pA2) DX(pA3) DX(pA4) DX(pA5)
        DY(pA0, pA1) DY(pA1, pA2) DY(pA2, pA3) DY(pA3, pA4) DY(pA4, pA5)
        if (hvA) DY(pA5, hlA)
        if (dzvA) {
            DZ(pA0, nA0) DZ(pA1, nA1) DZ(pA2, nA2)
            DZ(pA3, nA3) DZ(pA4, nA4) DZ(pA5, nA5)
        }
        // chain B compute
        DX(pB0) DX(pB1) DX(pB2) DX(pB3) DX(pB4) DX(pB5)
        DY(pB0, pB1) DY(pB1, pB2) DY(pB2, pB3) DY(pB3, pB4) DY(pB4, pB5)
        if (hvB) DY(pB5, hlB)
        if (dzvB) {
            DZ(pB0, nB0) DZ(pB1, nB1) DZ(pB2, nB2)
            DZ(pB3, nB3) DZ(pB4, nB4) DZ(pB5, nB5)
        }

        pA0 = nA0; pA1 = nA1; pA2 = nA2; pA3 = nA3; pA4 = nA4; pA5 = nA5;
        pB0 = nB0; pB1 = nB1; pB2 = nB2; pB3 = nB3; pB4 = nB4; pB5 = nB5;
        curA += PL4; curB += PL4;
    }
#undef DX
#undef DY
#undef DZ

    if (!al) { sx = 0.f; sy = 0.f; sz = 0.f; }    // clamped lanes: drop dupes

    #pragma unroll
    for (int off = 32; off > 0; off >>= 1) {
        sx += __shfl_down(sx, off);
        sy += __shfl_down(sy, off);
        sz += __shfl_down(sz, off);
    }
    __shared__ float px[WPB], py[WPB], pz[WPB];
    if (lane == 0) { px[wid] = sx; py[wid] = sy; pz[wid] = sz; }
    __syncthreads();
    if (threadIdx.x == 0) {
        float tx = 0.f, ty = 0.f, tz = 0.f;
        #pragma unroll
        for (int i = 0; i < WPB; ++i) { tx += px[i]; ty += py[i]; tz += pz[i]; }
        atomicAdd(&gs[0], (double)tx);
        atomicAdd(&gs[1], (double)ty);
        atomicAdd(&gs[2], (double)tz);
    }
}

// 1224 blocks of 256 threads: diff blocks [0,384) first (~1.5/CU, covers
// ALL CUs through the tail), hist blocks [384,1224) behind.
// launch_bounds(256,4): 16 waves/CU, VGPR cap 128 (dual-chain needs ~110).
__global__ __launch_bounds__(256, 4) void fused_kernel(
        const int4* __restrict__ f4,
        const int4* __restrict__ m4,
        unsigned int* __restrict__ gj,
        const float4* __restrict__ v4,
        double* __restrict__ gs) {
    if (blockIdx.x < DIFF_BLOCKS) diff_path(blockIdx.x, v4, gs);
    else                          hist_path(blockIdx.x - DIFF_BLOCKS, f4, m4, gj);
}

__global__ void finalize_kernel(const unsigned int* __restrict__ gj,
                                const double* __restrict__ gs,
                                float* __restrict__ out) {
    int lane = threadIdx.x & 63;
    float term = 0.f;
    if (lane >= 1 && lane < NC) {
        float fv = 0.f, mv = 0.f;
        #pragma unroll
        for (int m = 0; m < NC; ++m) fv += (float)gj[lane * JSTRIDE + m];
        #pragma unroll
        for (int f = 0; f < NC; ++f) mv += (float)gj[f * JSTRIDE + lane];
        float iv = (float)gj[lane * JSTRIDE + lane];
        term = (2.f * iv + 1e-5f) / (fv + mv + 1e-5f);
    }
    #pragma unroll
    for (int off = 32; off > 0; off >>= 1) term += __shfl_down(term, off);
    if (threadIdx.x == 0 && blockIdx.x == 0) {
        float sim = 1.f - term * (1.f / 25.f);
        double mdx = gs[0] / ((double)3 * Dd * Hh * (Ww - 1));
        double mdy = gs[1] / ((double)3 * Dd * (Hh - 1) * Ww);
        double mdz = gs[2] / ((double)3 * (Dd - 1) * Hh * Ww);
        float smooth = (float)((mdx + mdy + mdz) / 3.0);
        out[0] = sim + smooth;
        out[1] = sim;
        out[2] = smooth;
    }
}

extern "C" void kernel_launch(void* const* d_in, const int* in_sizes, int n_in,
                              void* d_out, int out_size, void* d_ws, size_t ws_size,
                              hipStream_t stream) {
    const int*   fl = (const int*)d_in[0];
    const int*   ml = (const int*)d_in[1];
    const float* vf = (const float*)d_in[2];
    float* out = (float*)d_out;

    // workspace: [0, 3432) joint counts (858 uints); [3584, 3608) double sums[3]
    // One memset node zeroes the whole footprint (0.0 double == all-zero).
    unsigned int* joint = (unsigned int*)d_ws;
    double*       sums  = (double*)((char*)d_ws + 3584);

    hipMemsetAsync(d_ws, 0, 3608, stream);
    fused_kernel<<<FUSED_BLOCKS, TPB, 0, stream>>>(
        (const int4*)fl, (const int4*)ml, joint, (const float4*)vf, sums);
    finalize_kernel<<<1, 64, 0, stream>>>(joint, sums, out);
}

// Round 9
// 174.676 us; speedup vs baseline: 1.2034x; 1.1877x over previous
//
#include <hip/hip_runtime.h>

// SynthMorphLoss: soft-dice over int32 label maps + diffusion regularizer.
// B=1, D=160, H=192, W=224, 26 classes (class 0 ignored in dice mean).
// R15 == R12 verbatim (session best: fused 58.3us, total 175.2us).
// R14 post-mortem: launch_bounds(256,4) capped VGPR at 128; compiler chose
// 64 + spilled the dual-chain live set (WRITE_SIZE 1.4->60.5 MB scratch),
// fused 58.3->89.2us. Reverting to the proven (512,2) config (84 VGPR, no
// spill). Session model, now fit by ALL rounds: duration == wave lane-bytes
// (incl. scratch) / ~2.9 TB/s — a chip-level request-throughput wall that
// wave count, block size/count, MLP depth, and launch bounds all failed to
// move (each <5%). Done-ticket sync: permanently dead (+46us, R13).
// Memset-vs-init-kernel: identical fixed cost (R14). Remaining headroom:
// ~11% diff-byte cut via LDS halo exchange (~4us) vs risk to verified state.

namespace {
constexpr int NC    = 26;
constexpr int Dd    = 160, Hh = 192, Ww = 224;
constexpr int W4    = Ww / 4;                 // 56 float4 per row
constexpr int PL4   = Hh * W4;                // 10752 float4 per (c,d) plane
constexpr int N4L   = Dd * Hh * Ww / 4;       // 1,720,320 int4 per label map
constexpr int JSTRIDE = 33;                   // joint-hist row stride
constexpr int NBINS   = NC * JSTRIDE;         // 858
constexpr int TPB     = 512;                  // 8 waves per block
constexpr int WPB     = TPB / 64;             // 8
// hist: 420 blocks x 512 threads x 8 int4 per map (420*512*8 == N4L exact)
constexpr int HIST_BLOCKS = 420;
constexpr int HT          = HIST_BLOCKS * TPB;     // 215040
// diff: tile = (c, 6-row h-slab, 5-plane d-chunk); 3072 tiles total.
// Each wave owns TWO tiles: w and w + 1536.
constexpr int SLAB    = 6;                    // rows per tile
constexpr int DCH     = 5;                    // d-steps per tile
constexpr int NTILES  = 3 * (Dd / DCH) * (Hh / SLAB);  // 3072
constexpr int DIFF_WAVES  = NTILES / 2;                // 1536
constexpr int DIFF_BLOCKS = DIFF_WAVES / WPB;          // 192
constexpr int FUSED_BLOCKS = DIFF_BLOCKS + HIST_BLOCKS;  // 612
}

__global__ void init_ws_kernel(unsigned int* __restrict__ joint,
                               double* __restrict__ sums) {
    int i = blockIdx.x * blockDim.x + threadIdx.x;
    if (i < NBINS) joint[i] = 0u;
    if (i < 3)     sums[i]  = 0.0;
}

// ---- hist path: same per-thread work as R6-R12 (8 int4 per map) ----
__device__ __forceinline__ void hist_path(
        int hb,
        const int4* __restrict__ f4,
        const int4* __restrict__ m4,
        unsigned int* __restrict__ gj) {
    __shared__ unsigned int h[NBINS];
    for (int i = threadIdx.x; i < NBINS; i += TPB) h[i] = 0u;
    __syncthreads();

    const int g = hb * TPB + threadIdx.x;
    int4 a0 = f4[g];
    int4 a1 = f4[g + HT];
    int4 a2 = f4[g + 2 * HT];
    int4 a3 = f4[g + 3 * HT];
    int4 a4 = f4[g + 4 * HT];
    int4 a5 = f4[g + 5 * HT];
    int4 a6 = f4[g + 6 * HT];
    int4 a7 = f4[g + 7 * HT];
    int4 b0 = m4[g];
    int4 b1 = m4[g + HT];
    int4 b2 = m4[g + 2 * HT];
    int4 b3 = m4[g + 3 * HT];
    int4 b4 = m4[g + 4 * HT];
    int4 b5 = m4[g + 5 * HT];
    int4 b6 = m4[g + 6 * HT];
    int4 b7 = m4[g + 7 * HT];

#define JACC(A, B)                                   \
    atomicAdd(&h[(A).x * JSTRIDE + (B).x], 1u);      \
    atomicAdd(&h[(A).y * JSTRIDE + (B).y], 1u);      \
    atomicAdd(&h[(A).z * JSTRIDE + (B).z], 1u);      \
    atomicAdd(&h[(A).w * JSTRIDE + (B).w], 1u);
    JACC(a0, b0) JACC(a1, b1) JACC(a2, b2) JACC(a3, b3)
    JACC(a4, b4) JACC(a5, b5) JACC(a6, b6) JACC(a7, b7)
#undef JACC

    __syncthreads();
    for (int i = threadIdx.x; i < NBINS; i += TPB) {
        unsigned int v = h[i];
        if (v) atomicAdd(&gj[i], v);
    }
}

// ---- diff path: TWO independent z-carry chains per wave (R12 verbatim) ----
// Tile t: c = t>>10, dchunk = (t&1023)>>5, slab = t&31.
__device__ __forceinline__ void diff_path(
        int db,
        const float4* __restrict__ v4,
        double* __restrict__ gs) {
    const int lane = threadIdx.x & 63;
    const int wid  = threadIdx.x >> 6;
    const int w    = db * WPB + wid;          // 0..1535
    const bool al  = (lane < W4);
    const int  l   = al ? lane : (W4 - 1);    // clamp inactive lanes

    // tile A
    const int tA = w;
    const int cA = tA >> 10, remA = tA & 1023;
    const int d0A = (remA >> 5) * DCH;
    const int h0A = (remA & 31) * SLAB;
    const bool hvA = (h0A + SLAB < Hh);
    const int hOffA = (hvA ? SLAB : SLAB - 1) * W4;
    size_t curA = ((size_t)(cA * Dd + d0A) * Hh + h0A) * W4 + l;
    // tile B
    const int tB = w + DIFF_WAVES;
    const int cB = tB >> 10, remB = tB & 1023;
    const int d0B = (remB >> 5) * DCH;
    const int h0B = (remB & 31) * SLAB;
    const bool hvB = (h0B + SLAB < Hh);
    const int hOffB = (hvB ? SLAB : SLAB - 1) * W4;
    size_t curB = ((size_t)(cB * Dd + d0B) * Hh + h0B) * W4 + l;

    float4 pA0 = v4[curA];
    float4 pA1 = v4[curA + W4];
    float4 pA2 = v4[curA + 2 * W4];
    float4 pA3 = v4[curA + 3 * W4];
    float4 pA4 = v4[curA + 4 * W4];
    float4 pA5 = v4[curA + 5 * W4];
    float4 pB0 = v4[curB];
    float4 pB1 = v4[curB + W4];
    float4 pB2 = v4[curB + 2 * W4];
    float4 pB3 = v4[curB + 3 * W4];
    float4 pB4 = v4[curB + 4 * W4];
    float4 pB5 = v4[curB + 5 * W4];

    float sx = 0.f, sy = 0.f, sz = 0.f;

#define DX(P)                                                                  \
    {                                                                          \
        float d1 = (P).y - (P).x, d2 = (P).z - (P).y, d3 = (P).w - (P).z;      \
        sx += d1 * d1 + d2 * d2 + d3 * d3;                                     \
        float nx = __shfl_down((P).x, 1);                                      \
        float d4 = nx - (P).w;                                                 \
        sx += (lane < W4 - 1) ? d4 * d4 : 0.f;                                 \
    }
#define DY(A, B)                                                               \
    {                                                                          \
        float e0 = (B).x - (A).x, e1 = (B).y - (A).y;                          \
        float e2 = (B).z - (A).z, e3 = (B).w - (A).w;                          \
        sy += e0 * e0 + e1 * e1 + e2 * e2 + e3 * e3;                           \
    }
#define DZ(A, B)                                                               \
    {                                                                          \
        float e0 = (B).x - (A).x, e1 = (B).y - (A).y;                          \
        float e2 = (B).z - (A).z, e3 = (B).w - (A).w;                          \
        sz += e0 * e0 + e1 * e1 + e2 * e2 + e3 * e3;                           \
    }

    for (int k = 0; k < DCH; ++k) {
        const bool dzvA = (d0A + k < Dd - 1);     // wave-uniform
        const bool dzvB = (d0B + k < Dd - 1);
        // issue BOTH halo loads + BOTH next-plane clusters up front
        float4 hlA = v4[curA + hOffA];
        float4 hlB = v4[curB + hOffB];
        float4 nA0 = pA0, nA1 = pA1, nA2 = pA2, nA3 = pA3, nA4 = pA4, nA5 = pA5;
        if (dzvA) {
            const size_t nb = curA + PL4;
            nA0 = v4[nb];
            nA1 = v4[nb + W4];
            nA2 = v4[nb + 2 * W4];
            nA3 = v4[nb + 3 * W4];
            nA4 = v4[nb + 4 * W4];
            nA5 = v4[nb + 5 * W4];
        }
        float4 nB0 = pB0, nB1 = pB1, nB2 = pB2, nB3 = pB3, nB4 = pB4, nB5 = pB5;
        if (dzvB) {
            const size_t nb = curB + PL4;
            nB0 = v4[nb];
            nB1 = v4[nb + W4];
            nB2 = v4[nb + 2 * W4];
            nB3 = v4[nb + 3 * W4];
            nB4 = v4[nb + 4 * W4];
            nB5 = v4[nb + 5 * W4];
        }

        // chain A compute
        DX(pA0) DX(pA1) DX(pA2) DX(pA3) DX(pA4) DX(pA5)
        DY(pA0, pA1) DY(pA1, pA2) DY(pA2, pA3) DY(pA3, pA4) DY(pA4, pA5)
        if (hvA) DY(pA5, hlA)
        if (dzvA) {
            DZ(pA0, nA0) DZ(pA1, nA1) DZ(pA2, nA2)
            DZ(pA3, nA3) DZ(pA4, nA4) DZ(pA5, nA5)
        }
        // chain B compute
        DX(pB0) DX(pB1) DX(pB2) DX(pB3) DX(pB4) DX(pB5)
        DY(pB0, pB1) DY(pB1, pB2) DY(pB2, pB3) DY(pB3, pB4) DY(pB4, pB5)
        if (hvB) DY(pB5, hlB)
        if (dzvB) {
            DZ(pB0, nB0) DZ(pB1, nB1) DZ(pB2, nB2)
            DZ(pB3, nB3) DZ(pB4, nB4) DZ(pB5, nB5)
        }

        pA0 = nA0; pA1 = nA1; pA2 = nA2; pA3 = nA3; pA4 = nA4; pA5 = nA5;
        pB0 = nB0; pB1 = nB1; pB2 = nB2; pB3 = nB3; pB4 = nB4; pB5 = nB5;
        curA += PL4; curB += PL4;
    }
#undef DX
#undef DY
#undef DZ

    if (!al) { sx = 0.f; sy = 0.f; sz = 0.f; }    // clamped lanes: drop dupes

    #pragma unroll
    for (int off = 32; off > 0; off >>= 1) {
        sx += __shfl_down(sx, off);
        sy += __shfl_down(sy, off);
        sz += __shfl_down(sz, off);
    }
    __shared__ float px[WPB], py[WPB], pz[WPB];
    if (lane == 0) { px[wid] = sx; py[wid] = sy; pz[wid] = sz; }
    __syncthreads();
    if (threadIdx.x == 0) {
        float tx = 0.f, ty = 0.f, tz = 0.f;
        #pragma unroll
        for (int i = 0; i < WPB; ++i) { tx += px[i]; ty += py[i]; tz += pz[i]; }
        atomicAdd(&gs[0], (double)tx);
        atomicAdd(&gs[1], (double)ty);
        atomicAdd(&gs[2], (double)tz);
    }
}

// 612 blocks of 512 threads: diff blocks [0,192) first (long-running,
// dual-chain), hist blocks [192,612) behind them (short, fill in as CUs
// free up). launch_bounds(512,2): VGPR cap 256 — dual-chain fits (84), no spill.
__global__ __launch_bounds__(512, 2) void fused_kernel(
        const int4* __restrict__ f4,
        const int4* __restrict__ m4,
        unsigned int* __restrict__ gj,
        const float4* __restrict__ v4,
        double* __restrict__ gs) {
    if (blockIdx.x < DIFF_BLOCKS) diff_path(blockIdx.x, v4, gs);
    else                          hist_path(blockIdx.x - DIFF_BLOCKS, f4, m4, gj);
}

__global__ void finalize_kernel(const unsigned int* __restrict__ gj,
                                const double* __restrict__ gs,
                                float* __restrict__ out) {
    int lane = threadIdx.x & 63;
    float term = 0.f;
    if (lane >= 1 && lane < NC) {
        float fv = 0.f, mv = 0.f;
        #pragma unroll
        for (int m = 0; m < NC; ++m) fv += (float)gj[lane * JSTRIDE + m];
        #pragma unroll
        for (int f = 0; f < NC; ++f) mv += (float)gj[f * JSTRIDE + lane];
        float iv = (float)gj[lane * JSTRIDE + lane];
        term = (2.f * iv + 1e-5f) / (fv + mv + 1e-5f);
    }
    #pragma unroll
    for (int off = 32; off > 0; off >>= 1) term += __shfl_down(term, off);
    if (threadIdx.x == 0 && blockIdx.x == 0) {
        float sim = 1.f - term * (1.f / 25.f);
        double mdx = gs[0] / ((double)3 * Dd * Hh * (Ww - 1));
        double mdy = gs[1] / ((double)3 * Dd * (Hh - 1) * Ww);
        double mdz = gs[2] / ((double)3 * (Dd - 1) * Hh * Ww);
        float smooth = (float)((mdx + mdy + mdz) / 3.0);
        out[0] = sim + smooth;
        out[1] = sim;
        out[2] = smooth;
    }
}

extern "C" void kernel_launch(void* const* d_in, const int* in_sizes, int n_in,
                              void* d_out, int out_size, void* d_ws, size_t ws_size,
                              hipStream_t stream) {
    const int*   fl = (const int*)d_in[0];
    const int*   ml = (const int*)d_in[1];
    const float* vf = (const float*)d_in[2];
    float* out = (float*)d_out;

    // workspace: [0, 3432) joint counts (858 uints); [3584, 3608) double sums[3]
    unsigned int* joint = (unsigned int*)d_ws;
    double*       sums  = (double*)((char*)d_ws + 3584);

    init_ws_kernel<<<1, 1024, 0, stream>>>(joint, sums);
    fused_kernel<<<FUSED_BLOCKS, TPB, 0, stream>>>(
        (const int4*)fl, (const int4*)ml, joint, (const float4*)vf, sums);
    finalize_kernel<<<1, 64, 0, stream>>>(joint, sums, out);
}